// Round 2
// baseline (126.237 us; speedup 1.0000x reference)
//
#include <hip/hip_runtime.h>
#include <math.h>

#define MA 64
#define ME 256
#define DM 256
#define DQK 32
#define NT 256
#define MASKVAL -998244352.0f   // bf16-rounded -1e9, matches reference's masked logit

__device__ __forceinline__ int lower_bound(const int* __restrict__ a, int n, int v){
  int lo = 0, hi = n;
  while (lo < hi){ int mid = (lo + hi) >> 1; if (a[mid] < v) lo = mid + 1; else hi = mid; }
  return lo;
}

__global__ __launch_bounds__(NT)
void fused_action_head(
    const float* __restrict__ x,  const float* __restrict__ Wq, const float* __restrict__ bq,
    const float* __restrict__ Wk, const float* __restrict__ bk,
    const int* __restrict__ actors, const int* __restrict__ qindices,
    const int* __restrict__ actees, const int* __restrict__ kindices,
    const int* __restrict__ prev_actions,
    int A, int E, float* __restrict__ out)
{
  __shared__ float wf[DM * DQK];        // 32 KB: Wk staged f32, then reused for Wq
  __shared__ float qs[MA][DQK + 4];     // padded rows (36 floats, 16B-aligned)
  __shared__ float rowS[4][ME];         // raw scores for current 4-row batch
  __shared__ float redM[4][4], redE[4][4], redT[4][4];

  const int t  = threadIdx.x;
  const int b  = blockIdx.x;
  const int wv = t >> 6;

  const int qstart = lower_bound(qindices, A, b * MA);
  const int qlen   = lower_bound(qindices, A, (b + 1) * MA) - qstart;
  const int kstart = lower_bound(kindices, E, b * ME);
  const int klen   = lower_bound(kindices, E, (b + 1) * ME) - kstart;

  // ---- stage Wk in LDS ----
  for (int i = t; i < (DM * DQK) / 4; i += NT)
    reinterpret_cast<float4*>(wf)[i] = reinterpret_cast<const float4*>(Wk)[i];
  __syncthreads();

  // ---- keys: thread t owns key t, kept in registers ----
  float kreg[DQK];
  #pragma unroll
  for (int d = 0; d < DQK; ++d) kreg[d] = 0.f;
  if (t < klen) {
    const float* xr = x + (size_t)actees[kstart + t] * DM;
    for (int m = 0; m < DM; m += 4) {
      float4 xv = *reinterpret_cast<const float4*>(xr + m);
      float xf[4] = {xv.x, xv.y, xv.z, xv.w};
      #pragma unroll
      for (int mm = 0; mm < 4; ++mm) {
        const float4* wrow = reinterpret_cast<const float4*>(&wf[(m + mm) * DQK]);
        #pragma unroll
        for (int dd = 0; dd < 8; ++dd) {
          float4 w4 = wrow[dd];
          kreg[dd*4+0] += xf[mm] * w4.x;
          kreg[dd*4+1] += xf[mm] * w4.y;
          kreg[dd*4+2] += xf[mm] * w4.z;
          kreg[dd*4+3] += xf[mm] * w4.w;
        }
      }
    }
    #pragma unroll
    for (int d = 0; d < DQK; ++d) kreg[d] += bk[d];
  }
  __syncthreads();   // done reading wf (Wk)

  // ---- stage Wq in LDS (same region) ----
  for (int i = t; i < (DM * DQK) / 4; i += NT)
    reinterpret_cast<float4*>(wf)[i] = reinterpret_cast<const float4*>(Wq)[i];
  __syncthreads();

  // ---- queries: 4 threads per query, 8 dims each ----
  {
    const int qi = t >> 2, dg = t & 3;
    if (qi < qlen) {
      float qa[8] = {0,0,0,0,0,0,0,0};
      const float* xr = x + (size_t)actors[qstart + qi] * DM;
      for (int m = 0; m < DM; m += 4) {
        float4 xv = *reinterpret_cast<const float4*>(xr + m);
        float xf[4] = {xv.x, xv.y, xv.z, xv.w};
        #pragma unroll
        for (int mm = 0; mm < 4; ++mm) {
          const float4* wrow = reinterpret_cast<const float4*>(&wf[(m + mm) * DQK + dg * 8]);
          float4 a0 = wrow[0], a1 = wrow[1];
          qa[0] += xf[mm] * a0.x; qa[1] += xf[mm] * a0.y;
          qa[2] += xf[mm] * a0.z; qa[3] += xf[mm] * a0.w;
          qa[4] += xf[mm] * a1.x; qa[5] += xf[mm] * a1.y;
          qa[6] += xf[mm] * a1.z; qa[7] += xf[mm] * a1.w;
        }
      }
      #pragma unroll
      for (int j = 0; j < 8; ++j) qa[j] += bq[dg * 8 + j];
      *reinterpret_cast<float4*>(&qs[qi][dg * 8])     = make_float4(qa[0], qa[1], qa[2], qa[3]);
      *reinterpret_cast<float4*>(&qs[qi][dg * 8 + 4]) = make_float4(qa[4], qa[5], qa[6], qa[7]);
    }
  }
  __syncthreads();

  // ---- logits + softmax, 4 rows per batch ----
  float* out_act = out;
  float* out_lp  = out + A;
  float* out_ent = out + 2 * A;
  float* out_lg  = out + (size_t)3 * A + (size_t)b * (MA * ME);
  const float SCALE = 0.17677669529663687f;   // 1/sqrt(32)

  for (int q0 = 0; q0 < MA; q0 += 4) {
    float sv[4];
    #pragma unroll
    for (int rr = 0; rr < 4; ++rr) {
      const int q = q0 + rr;
      float s = MASKVAL;
      if (q < qlen && t < klen) {
        const float4* qv = reinterpret_cast<const float4*>(&qs[q][0]);
        float acc = 0.f;
        #pragma unroll
        for (int dd = 0; dd < 8; ++dd) {
          float4 v = qv[dd];
          acc += v.x * kreg[dd*4+0] + v.y * kreg[dd*4+1]
               + v.z * kreg[dd*4+2] + v.w * kreg[dd*4+3];
        }
        s = acc * SCALE;
      }
      sv[rr] = s;
      rowS[rr][t] = s;
      float wm = s;
      #pragma unroll
      for (int off = 32; off; off >>= 1) wm = fmaxf(wm, __shfl_xor(wm, off));
      if ((t & 63) == 0) redM[rr][wv] = wm;
    }
    __syncthreads();

    float m4[4];
    #pragma unroll
    for (int rr = 0; rr < 4; ++rr) {
      float m = fmaxf(fmaxf(redM[rr][0], redM[rr][1]),
                      fmaxf(redM[rr][2], redM[rr][3]));
      m4[rr] = m;
      float d = sv[rr] - m;
      float e, tt;
      if (d > -80.f) { e = expf(d); tt = e * d; }   // valid lanes
      else           { e = 0.f;     tt = 0.f;    }  // masked lanes: exactly zero, no NaN path
      float se = e, st = tt;
      #pragma unroll
      for (int off = 32; off; off >>= 1) { se += __shfl_xor(se, off); st += __shfl_xor(st, off); }
      if ((t & 63) == 0) { redE[rr][wv] = se; redT[rr][wv] = st; }
    }
    __syncthreads();

    #pragma unroll
    for (int rr = 0; rr < 4; ++rr) {
      const int q = q0 + rr;
      out_lg[q * ME + t] = sv[rr];
      if (q < qlen && t == 0) {
        float S = redE[rr][0] + redE[rr][1] + redE[rr][2] + redE[rr][3];
        float T = redT[rr][0] + redT[rr][1] + redT[rr][2] + redT[rr][3];
        S = fmaxf(S, 1e-30f);
        float logS = logf(S);
        int pa = prev_actions[qstart + q];
        pa = pa < 0 ? 0 : (pa >= ME ? ME - 1 : pa);
        out_lp[qstart + q]  = rowS[rr][pa] - m4[rr] - logS;
        out_ent[qstart + q] = logS - T / S;
        out_act[qstart + q] = (float)pa;
      }
    }
    __syncthreads();   // rowS/red reused next batch
  }
}

extern "C" void kernel_launch(void* const* d_in, const int* in_sizes, int n_in,
                              void* d_out, int out_size, void* d_ws, size_t ws_size,
                              hipStream_t stream) {
  const float* x  = (const float*)d_in[0];
  const float* Wq = (const float*)d_in[1];
  const float* bq = (const float*)d_in[2];
  const float* Wk = (const float*)d_in[3];
  const float* bk = (const float*)d_in[4];
  const int* actors       = (const int*)d_in[5];
  const int* qindices     = (const int*)d_in[6];
  const int* actees       = (const int*)d_in[7];
  const int* kindices     = (const int*)d_in[8];
  const int* prev_actions = (const int*)d_in[9];

  const int A = in_sizes[5];
  const int E = in_sizes[8];
  const int B = (out_size - 3 * A) / (MA * ME);
  if (B <= 0) return;

  fused_action_head<<<dim3(B), dim3(NT), 0, stream>>>(
      x, Wq, bq, Wk, bk, actors, qindices, actees, kindices, prev_actions,
      A, E, (float*)d_out);
}

// Round 3
// 104.831 us; speedup vs baseline: 1.2042x; 1.2042x over previous
//
#include <hip/hip_runtime.h>
#include <math.h>

#define MA 64
#define ME 256
#define DM 256
#define DQK 32
#define NT 256
#define MASKVAL -998244352.0f          // bf16-rounded -1e9 (matches reference)
#define QK_SCALE 0.17677669529663687f  // 1/sqrt(32)

typedef long long i64;

__device__ __forceinline__ int lower_bound_dev(const int* __restrict__ a, int n, int v){
  int lo = 0, hi = n;
  while (lo < hi){ int mid = (lo + hi) >> 1; if (a[mid] < v) lo = mid + 1; else hi = mid; }
  return lo;
}

__global__ void ranges_kernel(const int* __restrict__ qindices, const int* __restrict__ kindices,
                              int A, int E, int B, int4* __restrict__ rng){
  int e = blockIdx.x * blockDim.x + threadIdx.x;
  if (e >= B) return;
  int qs = lower_bound_dev(qindices, A, e * MA);
  int qe = lower_bound_dev(qindices, A, e * MA + MA);
  int ks = lower_bound_dev(kindices, E, e * ME);
  int ke = lower_bound_dev(kindices, E, e * ME + ME);
  rng[e] = make_int4(qs, qe - qs, ks, ke - ks);
}

__device__ __forceinline__ float4 f4fma(float s, float4 a, float4 acc){
  acc.x += s * a.x; acc.y += s * a.y; acc.z += s * a.z; acc.w += s * a.w; return acc;
}

__global__ __launch_bounds__(NT)
void fused_head(const float* __restrict__ x,  const float* __restrict__ Wq, const float* __restrict__ bq,
               const float* __restrict__ Wk, const float* __restrict__ bk,
               const int* __restrict__ actors, const int* __restrict__ actees,
               const int* __restrict__ prev_actions, const int4* __restrict__ rng,
               int A, float* __restrict__ out)
{
  __shared__ float kb[ME][36];   // keys, stride 36 floats (bank-spread)
  __shared__ float qs[MA][36];   // queries

  const int t = threadIdx.x;
  const int b = blockIdx.x;
  const int4 rg = rng[b];
  const int qstart = rg.x, qlen = rg.y, kstart = rg.z, klen = rg.w;

  // ========== keys: thread = (key-block of 8, col-group of 4). W read from global (coalesced, L2-hot).
  {
    const int kbi = t >> 3, cg = t & 7;
    const int k0 = kbi * 8;
    if (k0 < klen) {
      const float* xr0 = x + (size_t)actees[kstart + min(k0 + 0, klen - 1)] * DM;
      const float* xr1 = x + (size_t)actees[kstart + min(k0 + 1, klen - 1)] * DM;
      const float* xr2 = x + (size_t)actees[kstart + min(k0 + 2, klen - 1)] * DM;
      const float* xr3 = x + (size_t)actees[kstart + min(k0 + 3, klen - 1)] * DM;
      const float* xr4 = x + (size_t)actees[kstart + min(k0 + 4, klen - 1)] * DM;
      const float* xr5 = x + (size_t)actees[kstart + min(k0 + 5, klen - 1)] * DM;
      const float* xr6 = x + (size_t)actees[kstart + min(k0 + 6, klen - 1)] * DM;
      const float* xr7 = x + (size_t)actees[kstart + min(k0 + 7, klen - 1)] * DM;
      float4 acc[8];
      #pragma unroll
      for (int r = 0; r < 8; ++r) acc[r] = make_float4(0.f, 0.f, 0.f, 0.f);
      const float* wp = Wk + cg * 4;
      for (int m = 0; m < DM; m += 4) {
        float4 w0 = *(const float4*)(wp + (m + 0) * DQK);
        float4 w1 = *(const float4*)(wp + (m + 1) * DQK);
        float4 w2 = *(const float4*)(wp + (m + 2) * DQK);
        float4 w3 = *(const float4*)(wp + (m + 3) * DQK);
        float4 xv;
        xv = *(const float4*)(xr0 + m); acc[0]=f4fma(xv.x,w0,acc[0]); acc[0]=f4fma(xv.y,w1,acc[0]); acc[0]=f4fma(xv.z,w2,acc[0]); acc[0]=f4fma(xv.w,w3,acc[0]);
        xv = *(const float4*)(xr1 + m); acc[1]=f4fma(xv.x,w0,acc[1]); acc[1]=f4fma(xv.y,w1,acc[1]); acc[1]=f4fma(xv.z,w2,acc[1]); acc[1]=f4fma(xv.w,w3,acc[1]);
        xv = *(const float4*)(xr2 + m); acc[2]=f4fma(xv.x,w0,acc[2]); acc[2]=f4fma(xv.y,w1,acc[2]); acc[2]=f4fma(xv.z,w2,acc[2]); acc[2]=f4fma(xv.w,w3,acc[2]);
        xv = *(const float4*)(xr3 + m); acc[3]=f4fma(xv.x,w0,acc[3]); acc[3]=f4fma(xv.y,w1,acc[3]); acc[3]=f4fma(xv.z,w2,acc[3]); acc[3]=f4fma(xv.w,w3,acc[3]);
        xv = *(const float4*)(xr4 + m); acc[4]=f4fma(xv.x,w0,acc[4]); acc[4]=f4fma(xv.y,w1,acc[4]); acc[4]=f4fma(xv.z,w2,acc[4]); acc[4]=f4fma(xv.w,w3,acc[4]);
        xv = *(const float4*)(xr5 + m); acc[5]=f4fma(xv.x,w0,acc[5]); acc[5]=f4fma(xv.y,w1,acc[5]); acc[5]=f4fma(xv.z,w2,acc[5]); acc[5]=f4fma(xv.w,w3,acc[5]);
        xv = *(const float4*)(xr6 + m); acc[6]=f4fma(xv.x,w0,acc[6]); acc[6]=f4fma(xv.y,w1,acc[6]); acc[6]=f4fma(xv.z,w2,acc[6]); acc[6]=f4fma(xv.w,w3,acc[6]);
        xv = *(const float4*)(xr7 + m); acc[7]=f4fma(xv.x,w0,acc[7]); acc[7]=f4fma(xv.y,w1,acc[7]); acc[7]=f4fma(xv.z,w2,acc[7]); acc[7]=f4fma(xv.w,w3,acc[7]);
      }
      float4 bkv = *(const float4*)(bk + cg * 4);
      #pragma unroll
      for (int r = 0; r < 8; ++r) {
        acc[r].x += bkv.x; acc[r].y += bkv.y; acc[r].z += bkv.z; acc[r].w += bkv.w;
        if (k0 + r < klen) *(float4*)&kb[k0 + r][cg * 4] = acc[r];
      }
    }
  }

  // ========== queries: thread = (query-pair of 2, col-group of 4)
  {
    const int qbi = t >> 3, cg = t & 7;
    const int r0 = qbi * 2, r1 = r0 + 1;
    if (r0 < qlen) {
      const float* xa = x + (size_t)actors[qstart + r0] * DM;
      const float* xb = x + (size_t)actors[qstart + min(r1, qlen - 1)] * DM;
      float4 aa = make_float4(0.f,0.f,0.f,0.f), ab = aa;
      const float* wp = Wq + cg * 4;
      for (int m = 0; m < DM; m += 4) {
        float4 w0 = *(const float4*)(wp + (m + 0) * DQK);
        float4 w1 = *(const float4*)(wp + (m + 1) * DQK);
        float4 w2 = *(const float4*)(wp + (m + 2) * DQK);
        float4 w3 = *(const float4*)(wp + (m + 3) * DQK);
        float4 xv;
        xv = *(const float4*)(xa + m); aa=f4fma(xv.x,w0,aa); aa=f4fma(xv.y,w1,aa); aa=f4fma(xv.z,w2,aa); aa=f4fma(xv.w,w3,aa);
        xv = *(const float4*)(xb + m); ab=f4fma(xv.x,w0,ab); ab=f4fma(xv.y,w1,ab); ab=f4fma(xv.z,w2,ab); ab=f4fma(xv.w,w3,ab);
      }
      float4 bqv = *(const float4*)(bq + cg * 4);
      aa.x += bqv.x; aa.y += bqv.y; aa.z += bqv.z; aa.w += bqv.w;
      ab.x += bqv.x; ab.y += bqv.y; ab.z += bqv.z; ab.w += bqv.w;
      *(float4*)&qs[r0][cg * 4] = aa;
      if (r1 < qlen) *(float4*)&qs[r1][cg * 4] = ab;
    }
  }

  __syncthreads();

  // ========== logits + softmax: 8-lane group owns 2 rows; zero barriers.
  float* out_act = out;
  float* out_lp  = out + A;
  float* out_ent = out + 2 * A;
  float* out_lg  = out + (size_t)3 * A + (size_t)b * (MA * ME);

  const int g = t >> 3, j = t & 7;
  const int r0 = 2 * g, r1 = r0 + 1;

  if (r0 >= qlen) {
    const float4 mv = make_float4(MASKVAL, MASKVAL, MASKVAL, MASKVAL);
    #pragma unroll
    for (int c = 0; c < 8; ++c) {
      *(float4*)(out_lg + r0 * ME + j * 32 + c * 4) = mv;
      *(float4*)(out_lg + r1 * ME + j * 32 + c * 4) = mv;
    }
  } else {
    const bool v1 = (r1 < qlen);
    float4 qv0[8], qv1[8];
    #pragma unroll
    for (int c = 0; c < 8; ++c) qv0[c] = *(const float4*)&qs[r0][c * 4];
    const int r1s = v1 ? r1 : r0;
    #pragma unroll
    for (int c = 0; c < 8; ++c) qv1[c] = *(const float4*)&qs[r1s][c * 4];

    int pa0 = prev_actions[qstart + r0] & (ME - 1);
    int pa1 = (v1 ? prev_actions[qstart + r1] : 0) & (ME - 1);

    float s0[32], s1[32];
    float spa0 = MASKVAL, spa1 = MASKVAL;
    #pragma unroll
    for (int s = 0; s < 32; ++s) {
      const int k = j + 8 * s;
      float d0 = MASKVAL, d1 = MASKVAL;
      if (k < klen) {
        float a0 = 0.f, a1 = 0.f;
        #pragma unroll
        for (int c = 0; c < 8; ++c) {
          float4 kv = *(const float4*)&kb[k][c * 4];
          a0 += qv0[c].x * kv.x + qv0[c].y * kv.y + qv0[c].z * kv.z + qv0[c].w * kv.w;
          a1 += qv1[c].x * kv.x + qv1[c].y * kv.y + qv1[c].z * kv.z + qv1[c].w * kv.w;
        }
        d0 = a0 * QK_SCALE;
        d1 = v1 ? a1 * QK_SCALE : MASKVAL;
      }
      s0[s] = d0; s1[s] = d1;
      if (k == pa0) spa0 = d0;
      if (k == pa1) spa1 = d1;
    }

    // row maxes
    float m0 = s0[0], m1 = s1[0];
    #pragma unroll
    for (int s = 1; s < 32; ++s) { m0 = fmaxf(m0, s0[s]); m1 = fmaxf(m1, s1[s]); }
    #pragma unroll
    for (int off = 1; off < 8; off <<= 1) {
      m0 = fmaxf(m0, __shfl_xor(m0, off));
      m1 = fmaxf(m1, __shfl_xor(m1, off));
    }

    // exp sums
    float e0 = 0.f, t0 = 0.f, e1 = 0.f, t1 = 0.f;
    #pragma unroll
    for (int s = 0; s < 32; ++s) {
      float dd0 = s0[s] - m0;
      if (dd0 > -80.f) { float ee = expf(dd0); e0 += ee; t0 += ee * dd0; }
      float dd1 = s1[s] - m1;
      if (dd1 > -80.f) { float ee = expf(dd1); e1 += ee; t1 += ee * dd1; }
    }
    #pragma unroll
    for (int off = 1; off < 8; off <<= 1) {
      e0 += __shfl_xor(e0, off);  t0 += __shfl_xor(t0, off);
      e1 += __shfl_xor(e1, off);  t1 += __shfl_xor(t1, off);
      spa0 = fmaxf(spa0, __shfl_xor(spa0, off));
      spa1 = fmaxf(spa1, __shfl_xor(spa1, off));
    }

    // write logits (masked k already MASKVAL; row r1 masked -> s1 is all MASKVAL)
    #pragma unroll
    for (int s = 0; s < 32; ++s) {
      const int k = j + 8 * s;
      out_lg[r0 * ME + k] = s0[s];
      out_lg[r1 * ME + k] = v1 ? s1[s] : MASKVAL;
    }

    if (j == 0) {
      float lS0 = logf(fmaxf(e0, 1e-30f));
      out_lp [qstart + r0] = spa0 - m0 - lS0;
      out_ent[qstart + r0] = lS0 - t0 / e0;
      out_act[qstart + r0] = (float)pa0;
      if (v1) {
        float lS1 = logf(fmaxf(e1, 1e-30f));
        out_lp [qstart + r1] = spa1 - m1 - lS1;
        out_ent[qstart + r1] = lS1 - t1 / e1;
        out_act[qstart + r1] = (float)pa1;
      }
    }
  }
}

extern "C" void kernel_launch(void* const* d_in, const int* in_sizes, int n_in,
                              void* d_out, int out_size, void* d_ws, size_t ws_size,
                              hipStream_t stream) {
  const float* x  = (const float*)d_in[0];
  const float* Wq = (const float*)d_in[1];
  const float* bq = (const float*)d_in[2];
  const float* Wk = (const float*)d_in[3];
  const float* bk = (const float*)d_in[4];
  const int* actors       = (const int*)d_in[5];
  const int* qindices     = (const int*)d_in[6];
  const int* actees       = (const int*)d_in[7];
  const int* kindices     = (const int*)d_in[8];
  const int* prev_actions = (const int*)d_in[9];

  const int A = in_sizes[5];
  const int E = in_sizes[7];
  const int B = (out_size - 3 * A) / (MA * ME);
  if (B <= 0) return;

  int4* rng = (int4*)d_ws;
  ranges_kernel<<<dim3((B + NT - 1) / NT), dim3(NT), 0, stream>>>(qindices, kindices, A, E, B, rng);
  fused_head<<<dim3(B), dim3(NT), 0, stream>>>(
      x, Wq, bq, Wk, bk, actors, actees, prev_actions, rng, A, (float*)d_out);
}